// Round 1
// 288.717 us; speedup vs baseline: 1.0518x; 1.0518x over previous
//
#include <hip/hip_runtime.h>
#include <hip/hip_fp16.h>

#define SEQ 8192
#define DIM 1024
#define NN  4096
#define KEFF 2048                 // [x_hi | x_lo] along K
#define NT   32                   // K-tiles of 64 over KEFF
#define A_BYTES ((size_t)SEQ * KEFF * 2)   // 33.55 MB fp16
#define B_BYTES ((size_t)NN * DIM * 2)     //  8.39 MB fp16 (W_hi, consumed twice)

using f16x8 = __attribute__((ext_vector_type(8))) _Float16;
using f32x4 = __attribute__((ext_vector_type(4))) float;

typedef __attribute__((address_space(1))) unsigned char as1_u8;
typedef __attribute__((address_space(3))) unsigned char as3_u8;

__device__ __forceinline__ float fast_tanh(float x) {
    float e = __expf(2.0f * x);
    return 1.0f - 2.0f / (e + 1.0f);
}

// ---------------------------------------------------------------------------
// Convert: plain row-major fp16. A[s][k] = hi(x[s][k]), A[s][k+1024] = lo.
// B[n][k] = hi(W[n][k]). Thread = 8 consecutive fp32: 32B coalesced reads,
// 16B coalesced stores. Blocks 0..4095: x. Blocks 4096..6143: W.
__global__ __launch_bounds__(256) void convert_kernel(
        const float* __restrict__ x, const float* __restrict__ w,
        f16x8* __restrict__ A, f16x8* __restrict__ B) {
    const int tid = threadIdx.x;
    const int b   = blockIdx.x;
    if (b < 4096) {
        const int gid = b * 256 + tid;           // 0 .. 1M
        const int s   = gid >> 7;
        const int kc  = gid & 127;
        const float4* src = (const float4*)(x + (size_t)s * DIM + kc * 8);
        const float4 v0 = src[0], v1 = src[1];
        const float f[8] = {v0.x, v0.y, v0.z, v0.w, v1.x, v1.y, v1.z, v1.w};
        f16x8 hv, lv;
#pragma unroll
        for (int e = 0; e < 8; e++) {
            const _Float16 h = (_Float16)f[e];
            hv[e] = h;
            lv[e] = (_Float16)(f[e] - (float)h);
        }
        f16x8* dst = A + (size_t)s * (KEFF / 8) + kc;
        dst[0]   = hv;            // cols kc*8 .. +7        (hi)
        dst[128] = lv;            // cols kc*8+1024 .. +7   (lo)
    } else {
        const int gid = (b - 4096) * 256 + tid;  // 0 .. 0.5M
        const int n   = gid >> 7;
        const int kc  = gid & 127;
        const float4* src = (const float4*)(w + (size_t)n * DIM + kc * 8);
        const float4 v0 = src[0], v1 = src[1];
        const float f[8] = {v0.x, v0.y, v0.z, v0.w, v1.x, v1.y, v1.z, v1.w};
        f16x8 hv;
#pragma unroll
        for (int e = 0; e < 8; e++) hv[e] = (_Float16)f[e];
        B[(size_t)n * (DIM / 8) + kc] = hv;
    }
}

// ---------------------------------------------------------------------------
// 256x256 tile, BK=64, 8 waves (2M x 4N), 512 threads, 128 KiB LDS dbuf.
// 8-phase schedule (2 barriers/phase), counted vmcnt(6) once per K-tile,
// st-swizzle g' = g ^ (row&7) applied to pre-swizzled global_load_lds source
// and to the ds_read_b128 addresses (involution). B-frags held across the
// K-tile so ds_read volume = 24 x b128 / wave / K-tile. Stage stream:
//   P1: KT(t+1).Bh1 -> other buf (slot idle since prev group)
//   P2: KT(t+2).Ah0 -> cur buf   (A-h0 last read at P1)
//   P3: KT(t+2).Bh0 -> cur buf   (B-h0 last read at P1)
//   P4: KT(t+2).Ah1 -> cur buf   (A-h1 last read at P3); vmcnt(6); barrier
// Every stage target's last ds_read retired >=1 barrier before issue.
__global__ __launch_bounds__(512, 2) void gemm_tanh_kernel(
        const _Float16* __restrict__ A,   // [SEQ][KEFF]
        const _Float16* __restrict__ B,   // [NN][DIM]
        const float* __restrict__ bias,   // [NN]
        float* __restrict__ out) {        // [SEQ][NN] fp32
    __shared__ _Float16 lds[65536];       // 128 KB: A0 | B0 | A1 | B1 (32KB each)

    const int tid  = threadIdx.x;
    const int lane = tid & 63;
    const int wave = tid >> 6;            // 0..7
    const int wm   = wave >> 2;           // 0..1 (M)
    const int wn   = wave & 3;            // 0..3 (N)
    const int l15  = lane & 15;
    const int lq   = lane >> 4;           // 0..3

    // XCD-bijective swizzle (512 % 8 == 0): each XCD owns 2 qb columns ->
    // its 1 MB B slice stays L2-resident; A streams via L3.
    const int wgid = ((blockIdx.x & 7) << 6) | (blockIdx.x >> 3);
    const int qb = wgid >> 5;             // 0..15
    const int pb = wgid & 31;             // 0..31
    const int rowBase = pb << 8;
    const int colBase = qb << 8;

    // ds_read offsets: row = (blk16)*16 + l15 -> row&7 == l15&7 (lane const)
    const int sw  = l15 & 7;
    const int gk0 = ((lq)     ^ sw) << 4;         // ksub 0 granule, swizzled
    const int gk1 = ((4 + lq) ^ sw) << 4;         // ksub 1
    const int aOff = wm * 2048 + l15 * 128;       // + r*4096
    const int bOff = 32768 + wn * 2048 + l15 * 128; // + j*8192

    // staging: thread covers LDS off tid*16 within an 8KB chunk;
    // source granule inverse-swizzled so swizzled ds_reads see row-major data.
    const int srow = tid >> 3;                    // 0..63
    const int sg   = (tid & 7) ^ (srow & 7);
    const unsigned ldsWave = (unsigned)wave << 10;

    const _Float16* Ag = A + (size_t)(rowBase + srow) * KEFF + sg * 8;
    const _Float16* Bg = B + (size_t)(colBase + srow) * DIM  + sg * 8;
    char* ldsc = (char*)lds;

    auto stageA = [&](int kt, int h, int d) {
        const _Float16* g = Ag + (size_t)h * 128 * KEFF + kt * 64;
        const unsigned lo = (unsigned)d * 65536u + (unsigned)h * 16384u + ldsWave;
        __builtin_amdgcn_global_load_lds((const as1_u8*)g,
                                         (as3_u8*)(ldsc + lo), 16, 0, 0);
        __builtin_amdgcn_global_load_lds((const as1_u8*)(g + (size_t)64 * KEFF),
                                         (as3_u8*)(ldsc + lo + 8192), 16, 0, 0);
    };
    auto stageB = [&](int kt, int h, int d) {
        const _Float16* g = Bg + (size_t)h * 128 * DIM + (kt & 15) * 64;
        const unsigned lo = (unsigned)d * 65536u + 32768u + (unsigned)h * 16384u + ldsWave;
        __builtin_amdgcn_global_load_lds((const as1_u8*)g,
                                         (as3_u8*)(ldsc + lo), 16, 0, 0);
        __builtin_amdgcn_global_load_lds((const as1_u8*)(g + (size_t)64 * DIM),
                                         (as3_u8*)(ldsc + lo + 8192), 16, 0, 0);
    };

    f32x4 acc[8][4] = {};
    f16x8 aF[4][2], bF[4][2];

    // Prologue: KT0 -> buf0 (all 4 halves), KT1 -> buf1 (Ah0,Ah1,Bh0).
    stageA(0, 0, 0); stageA(0, 1, 0); stageB(0, 0, 0); stageB(0, 1, 0);
    stageA(1, 0, 1); stageA(1, 1, 1); stageB(1, 0, 1);
    asm volatile("s_waitcnt vmcnt(6)" ::: "memory");   // KT0 landed
    __builtin_amdgcn_s_barrier();

    for (int t = 0; t < NT; ++t) {
        const int d  = t & 1;
        const int dn = d ^ 1;
        const char* lb = ldsc + d * 65536;

        // ---- P1: quadrant (mh0, n0-1); stage KT(t+1).Bh1 -> buf dn
#pragma unroll
        for (int i = 0; i < 4; ++i) {
            aF[i][0] = *(const f16x8*)(lb + aOff + i * 4096 + gk0);
            aF[i][1] = *(const f16x8*)(lb + aOff + i * 4096 + gk1);
        }
#pragma unroll
        for (int j = 0; j < 2; ++j) {
            bF[j][0] = *(const f16x8*)(lb + bOff + j * 8192 + gk0);
            bF[j][1] = *(const f16x8*)(lb + bOff + j * 8192 + gk1);
        }
        if (t + 1 < NT) stageB(t + 1, 1, dn);
        __builtin_amdgcn_s_barrier();
        __builtin_amdgcn_s_setprio(1);
#pragma unroll
        for (int k = 0; k < 2; ++k)
#pragma unroll
            for (int i = 0; i < 4; ++i)
#pragma unroll
                for (int j = 0; j < 2; ++j)
                    acc[i][j] = __builtin_amdgcn_mfma_f32_16x16x32_f16(
                        aF[i][k], bF[j][k], acc[i][j], 0, 0, 0);
        __builtin_amdgcn_s_setprio(0);
        __builtin_amdgcn_s_barrier();

        // ---- P2: (mh0, n2-3); stage KT(t+2).Ah0 -> buf d
#pragma unroll
        for (int j = 2; j < 4; ++j) {
            bF[j][0] = *(const f16x8*)(lb + bOff + j * 8192 + gk0);
            bF[j][1] = *(const f16x8*)(lb + bOff + j * 8192 + gk1);
        }
        if (t + 2 < NT) stageA(t + 2, 0, d);
        __builtin_amdgcn_s_barrier();
        __builtin_amdgcn_s_setprio(1);
#pragma unroll
        for (int k = 0; k < 2; ++k)
#pragma unroll
            for (int i = 0; i < 4; ++i)
#pragma unroll
                for (int j = 2; j < 4; ++j)
                    acc[i][j] = __builtin_amdgcn_mfma_f32_16x16x32_f16(
                        aF[i][k], bF[j][k], acc[i][j], 0, 0, 0);
        __builtin_amdgcn_s_setprio(0);
        __builtin_amdgcn_s_barrier();

        // ---- P3: (mh1, n0-1); stage KT(t+2).Bh0 -> buf d
#pragma unroll
        for (int i = 0; i < 4; ++i) {
            aF[i][0] = *(const f16x8*)(lb + aOff + (4 + i) * 4096 + gk0);
            aF[i][1] = *(const f16x8*)(lb + aOff + (4 + i) * 4096 + gk1);
        }
        if (t + 2 < NT) stageB(t + 2, 0, d);
        __builtin_amdgcn_s_barrier();
        __builtin_amdgcn_s_setprio(1);
#pragma unroll
        for (int k = 0; k < 2; ++k)
#pragma unroll
            for (int i = 0; i < 4; ++i)
#pragma unroll
                for (int j = 0; j < 2; ++j)
                    acc[4 + i][j] = __builtin_amdgcn_mfma_f32_16x16x32_f16(
                        aF[i][k], bF[j][k], acc[4 + i][j], 0, 0, 0);
        __builtin_amdgcn_s_setprio(0);
        __builtin_amdgcn_s_barrier();

        // ---- P4: (mh1, n2-3); stage KT(t+2).Ah1 -> buf d; counted vmcnt
        if (t + 2 < NT) stageA(t + 2, 1, d);
        __builtin_amdgcn_s_barrier();
        __builtin_amdgcn_s_setprio(1);
#pragma unroll
        for (int k = 0; k < 2; ++k)
#pragma unroll
            for (int i = 0; i < 4; ++i)
#pragma unroll
                for (int j = 2; j < 4; ++j)
                    acc[4 + i][j] = __builtin_amdgcn_mfma_f32_16x16x32_f16(
                        aF[i][k], bF[j][k], acc[4 + i][j], 0, 0, 0);
        __builtin_amdgcn_s_setprio(0);
        if (t + 2 < NT) {
            asm volatile("s_waitcnt vmcnt(6)" ::: "memory");  // KT(t+1) landed
        } else if (t + 1 < NT) {
            asm volatile("s_waitcnt vmcnt(0)" ::: "memory");  // epilogue drain
        }
        __builtin_amdgcn_s_barrier();
    }

    // Epilogue: C/D col = lane&15, row = (lane>>4)*4 + reg. Wave rows are
    // 16-interleaved: row(r) = rowBase + (r*2+wm)*16; col(j) = (j*4+wn)*16.
#pragma unroll
    for (int j = 0; j < 4; ++j) {
        const int col = colBase + (j * 4 + wn) * 16 + l15;
        const float bj = bias[col];
#pragma unroll
        for (int r = 0; r < 8; ++r) {
            const size_t rb = (size_t)(rowBase + (r * 2 + wm) * 16 + lq * 4) * NN + col;
#pragma unroll
            for (int v = 0; v < 4; ++v)
                out[rb + (size_t)v * NN] = fast_tanh(acc[r][j][v] + bj);
        }
    }
}

// ---------------------------------------------------------------------------
// Fallback (only if workspace too small): naive fp32 tiled GEMM.
__global__ void naive_gemm_kernel(const float* __restrict__ x,
                                  const float* __restrict__ W,
                                  const float* __restrict__ b,
                                  float* __restrict__ out) {
    __shared__ float xs[16][17], ws[16][17];
    int n = blockIdx.x * 16 + threadIdx.x;
    int m = blockIdx.y * 16 + threadIdx.y;
    float s = 0.f;
    for (int k0 = 0; k0 < DIM; k0 += 16) {
        xs[threadIdx.y][threadIdx.x] = x[(size_t)m * DIM + k0 + threadIdx.x];
        ws[threadIdx.y][threadIdx.x] =
            W[(size_t)(blockIdx.x * 16 + threadIdx.y) * DIM + k0 + threadIdx.x];
        __syncthreads();
#pragma unroll
        for (int kk = 0; kk < 16; kk++) s += xs[threadIdx.y][kk] * ws[threadIdx.x][kk];
        __syncthreads();
    }
    out[(size_t)m * NN + n] = tanhf(s + b[n]);
}

// ---------------------------------------------------------------------------
extern "C" void kernel_launch(void* const* d_in, const int* in_sizes, int n_in,
                              void* d_out, int out_size, void* d_ws, size_t ws_size,
                              hipStream_t stream) {
    const float* x = (const float*)d_in[0];
    const float* W = (const float*)d_in[1];
    const float* b = (const float*)d_in[2];
    float* out = (float*)d_out;

    const size_t need = A_BYTES + B_BYTES;   // 41.94 MB (same as prior kernel)
    if (ws_size < need) {
        dim3 grid(NN / 16, SEQ / 16), block(16, 16);
        naive_gemm_kernel<<<grid, block, 0, stream>>>(x, W, b, out);
        return;
    }

    _Float16* Abuf = (_Float16*)d_ws;
    _Float16* Bbuf = Abuf + (size_t)SEQ * KEFF;

    convert_kernel<<<6144, 256, 0, stream>>>(x, W, (f16x8*)Abuf, (f16x8*)Bbuf);

    gemm_tanh_kernel<<<512, 512, 0, stream>>>(Abuf, Bbuf, b, out);
}

// Round 2
// 285.947 us; speedup vs baseline: 1.0620x; 1.0097x over previous
//
#include <hip/hip_runtime.h>
#include <hip/hip_fp16.h>

#define SEQ 8192
#define DIM 1024
#define NN  4096
#define KEFF 2048                 // [x_hi | x_lo] along K
#define NT   32                   // K-tiles of 64 over KEFF
#define A_BYTES ((size_t)SEQ * KEFF * 2)   // 33.55 MB fp16
#define B_BYTES ((size_t)NN * DIM * 2)     //  8.39 MB fp16 (W_hi, consumed twice)

using f16x8 = __attribute__((ext_vector_type(8))) _Float16;
using f16x4 = __attribute__((ext_vector_type(4))) _Float16;
using f32x4 = __attribute__((ext_vector_type(4))) float;

typedef __attribute__((address_space(1))) unsigned char as1_u8;
typedef __attribute__((address_space(3))) unsigned char as3_u8;

__device__ __forceinline__ float fast_tanh(float x) {
    float e = __expf(2.0f * x);
    return 1.0f - 2.0f / (e + 1.0f);
}

// ---------------------------------------------------------------------------
// Convert: fully unit-stride. One float4 per thread -> 16B coalesced loads,
// two 8B coalesced stores (hi, lo). A[s][k]=hi(x[s][k]), A[s][k+1024]=lo.
// B[n][k]=hi(W[n][k]). Blocks 0..8191: x. Blocks 8192..12287: W.
__global__ __launch_bounds__(256) void convert_kernel(
        const float* __restrict__ x, const float* __restrict__ w,
        f16x4* __restrict__ A, f16x4* __restrict__ B) {
    const int tid = threadIdx.x;
    const int b   = blockIdx.x;
    if (b < 8192) {
        const int gid = b * 256 + tid;          // 0 .. 2,097,151
        const int s   = gid >> 8;               // DIM/4 = 256 chunks per row
        const int c   = gid & 255;
        const float4 v = ((const float4*)x)[(size_t)s * 256 + c];
        const float f[4] = {v.x, v.y, v.z, v.w};
        f16x4 hv, lv;
#pragma unroll
        for (int e = 0; e < 4; e++) {
            const _Float16 h = (_Float16)f[e];
            hv[e] = h;
            lv[e] = (_Float16)(f[e] - (float)h);
        }
        f16x4* dst = A + (size_t)s * 512 + c;   // KEFF/4 = 512 chunks per row
        dst[0]   = hv;                          // k = c*4 ..      (hi)
        dst[256] = lv;                          // k = c*4+1024 .. (lo)
    } else {
        const int gid = (b - 8192) * 256 + tid; // 0 .. 1,048,575
        const int n   = gid >> 8;
        const int c   = gid & 255;
        const float4 v = ((const float4*)w)[(size_t)n * 256 + c];
        const float f[4] = {v.x, v.y, v.z, v.w};
        f16x4 hv;
#pragma unroll
        for (int e = 0; e < 4; e++) hv[e] = (_Float16)f[e];
        B[(size_t)n * 256 + c] = hv;
    }
}

// ---------------------------------------------------------------------------
// 256x256 tile, BK=64, 8 waves (2M x 4N), 128 KiB LDS dbuf, 8-phase with
// FRAGMENT READ-AHEAD: each phase's ds_reads feed the NEXT phase's MFMA, so
// the lgkm drain hides under the current MFMA cluster. Fragment sets each
// serve 2 phases (single-buffered rotation):
//   P1: MFMA(Ah0 x Bn01) | read Bn23(t)        | stage B(t+1)h1 -> dn
//   P2: MFMA(Ah0 x Bn23) | read Ah1(t)         | stage A(t+2)h0 -> d
//   P3: MFMA(Ah1 x Bn01) | (no reads)          | stage B(t+2)h0 -> d ; vmcnt(4)
//   P4: MFMA(Ah1 x Bn23) | read Ah0,Bn01(t+1)  | stage A(t+2)h1 -> d
// vmcnt(4) at P3 leaves only this iter's P2+P3 stages outstanding => all of
// KT(t+1) landed before P4's cross-buffer read-ahead. Race-freedom: every
// stage targets a region whose last ds_read completed >= 1 barrier earlier.
__global__ __launch_bounds__(512, 2) void gemm_tanh_kernel(
        const _Float16* __restrict__ A,   // [SEQ][KEFF]
        const _Float16* __restrict__ B,   // [NN][DIM]
        const float* __restrict__ bias,   // [NN]
        float* __restrict__ out) {        // [SEQ][NN] fp32
    __shared__ _Float16 lds[65536];       // 128 KB: (A 32K | B 32K) x 2 bufs

    const int tid  = threadIdx.x;
    const int lane = tid & 63;
    const int wave = tid >> 6;            // 0..7
    const int wm   = wave >> 2;           // 0..1 (M)
    const int wn   = wave & 3;            // 0..3 (N)
    const int l15  = lane & 15;
    const int lq   = lane >> 4;           // 0..3

    // XCD map: xcd owns pb in [4*xcd, 4*xcd+4); concurrent batch = 4pb x 8qb
    // => each A strip L2-hit by 8 blocks, each B slice by 4. Bijective.
    const int xcd = blockIdx.x & 7;
    const int idx = blockIdx.x >> 3;      // 0..63
    const int pb  = xcd * 4 + (idx & 3);  // 0..31
    const int qb  = idx >> 2;             // 0..15
    const int rowBase = pb << 8;
    const int colBase = qb << 8;

    // swizzled ds_read offsets: row&7 == l15&7 for every fragment row
    const int sw  = l15 & 7;
    const int gk0 = ((lq)     ^ sw) << 4;
    const int gk1 = ((4 + lq) ^ sw) << 4;
    const int aOff = wm * 2048 + l15 * 128;
    const int bOff = 32768 + wn * 2048 + l15 * 128;

    // staging: linear LDS dest (wave-uniform base + lane*16), inverse-swizzled
    // global source so swizzled ds_reads see row-major data.
    const int srow = tid >> 3;            // 0..63 within a 64-row chunk
    const int sg   = (tid & 7) ^ (srow & 7);
    const unsigned ldsWave = (unsigned)wave << 10;

    const _Float16* Ag = A + (size_t)(rowBase + srow) * KEFF + sg * 8;
    const _Float16* Bg = B + (size_t)(colBase + srow) * DIM  + sg * 8;
    char* ldsc = (char*)lds;

    auto stageA = [&](int kt, int h, int d) {
        const _Float16* g = Ag + (size_t)h * 128 * KEFF + kt * 64;
        const unsigned lo = (unsigned)d * 65536u + (unsigned)h * 16384u + ldsWave;
        __builtin_amdgcn_global_load_lds((const as1_u8*)g,
                                         (as3_u8*)(ldsc + lo), 16, 0, 0);
        __builtin_amdgcn_global_load_lds((const as1_u8*)(g + (size_t)64 * KEFF),
                                         (as3_u8*)(ldsc + lo + 8192), 16, 0, 0);
    };
    auto stageB = [&](int kt, int h, int d) {
        const _Float16* g = Bg + (size_t)h * 128 * DIM + (kt & 15) * 64;
        const unsigned lo = (unsigned)d * 65536u + 32768u + (unsigned)h * 16384u + ldsWave;
        __builtin_amdgcn_global_load_lds((const as1_u8*)g,
                                         (as3_u8*)(ldsc + lo), 16, 0, 0);
        __builtin_amdgcn_global_load_lds((const as1_u8*)(g + (size_t)64 * DIM),
                                         (as3_u8*)(ldsc + lo + 8192), 16, 0, 0);
    };

    f32x4 acc[8][4] = {};
    f16x8 aH0[4][2], aH1[4][2], bN01[2][2], bN23[2][2];

    // Prologue: KT0 fully -> buf0; KT1 Ah0,Bh0,Ah1 -> buf1 (Bh1 staged at t=0 P1)
    stageA(0, 0, 0); stageA(0, 1, 0); stageB(0, 0, 0); stageB(0, 1, 0);
    stageA(1, 0, 1); stageB(1, 0, 1); stageA(1, 1, 1);
    asm volatile("s_waitcnt vmcnt(6)" ::: "memory");   // KT0 landed
    __builtin_amdgcn_s_barrier();
    {   // pre-read P1 fragments of KT0
        const char* lb = ldsc;
#pragma unroll
        for (int i = 0; i < 4; ++i) {
            aH0[i][0] = *(const f16x8*)(lb + aOff + i * 4096 + gk0);
            aH0[i][1] = *(const f16x8*)(lb + aOff + i * 4096 + gk1);
        }
#pragma unroll
        for (int j = 0; j < 2; ++j) {
            bN01[j][0] = *(const f16x8*)(lb + bOff + j * 8192 + gk0);
            bN01[j][1] = *(const f16x8*)(lb + bOff + j * 8192 + gk1);
        }
    }

    for (int t = 0; t < NT; ++t) {
        const int d  = t & 1;
        const int dn = d ^ 1;
        const char* lb  = ldsc + d * 65536;
        const char* lbn = ldsc + dn * 65536;

        // ---- P1: MFMA(Ah0 x Bn01); read Bn23(t); stage B(t+1)h1 -> dn
#pragma unroll
        for (int j = 0; j < 2; ++j) {
            bN23[j][0] = *(const f16x8*)(lb + bOff + 16384 + j * 8192 + gk0);
            bN23[j][1] = *(const f16x8*)(lb + bOff + 16384 + j * 8192 + gk1);
        }
        if (t + 1 < NT) stageB(t + 1, 1, dn);
        __builtin_amdgcn_s_barrier();
        __builtin_amdgcn_s_setprio(1);
#pragma unroll
        for (int k = 0; k < 2; ++k)
#pragma unroll
            for (int i = 0; i < 4; ++i)
#pragma unroll
                for (int j = 0; j < 2; ++j)
                    acc[i][j] = __builtin_amdgcn_mfma_f32_16x16x32_f16(
                        aH0[i][k], bN01[j][k], acc[i][j], 0, 0, 0);
        __builtin_amdgcn_s_setprio(0);
        __builtin_amdgcn_s_barrier();

        // ---- P2: MFMA(Ah0 x Bn23); read Ah1(t); stage A(t+2)h0 -> d
#pragma unroll
        for (int i = 0; i < 4; ++i) {
            aH1[i][0] = *(const f16x8*)(lb + aOff + 16384 + i * 4096 + gk0);
            aH1[i][1] = *(const f16x8*)(lb + aOff + 16384 + i * 4096 + gk1);
        }
        if (t + 2 < NT) stageA(t + 2, 0, d);
        __builtin_amdgcn_s_barrier();
        __builtin_amdgcn_s_setprio(1);
#pragma unroll
        for (int k = 0; k < 2; ++k)
#pragma unroll
            for (int i = 0; i < 4; ++i)
#pragma unroll
                for (int j = 0; j < 2; ++j)
                    acc[i][2 + j] = __builtin_amdgcn_mfma_f32_16x16x32_f16(
                        aH0[i][k], bN23[j][k], acc[i][2 + j], 0, 0, 0);
        __builtin_amdgcn_s_setprio(0);
        __builtin_amdgcn_s_barrier();

        // ---- P3: MFMA(Ah1 x Bn01); stage B(t+2)h0 -> d; counted vmcnt
        if (t + 2 < NT) stageB(t + 2, 0, d);
        if (t + 2 < NT) {
            asm volatile("s_waitcnt vmcnt(4)" ::: "memory");  // KT(t+1) landed
        } else if (t + 1 < NT) {
            asm volatile("s_waitcnt vmcnt(0)" ::: "memory");  // tail drain
        }
        __builtin_amdgcn_s_barrier();
        __builtin_amdgcn_s_setprio(1);
#pragma unroll
        for (int k = 0; k < 2; ++k)
#pragma unroll
            for (int i = 0; i < 4; ++i)
#pragma unroll
                for (int j = 0; j < 2; ++j)
                    acc[4 + i][j] = __builtin_amdgcn_mfma_f32_16x16x32_f16(
                        aH1[i][k], bN01[j][k], acc[4 + i][j], 0, 0, 0);
        __builtin_amdgcn_s_setprio(0);
        __builtin_amdgcn_s_barrier();

        // ---- P4: MFMA(Ah1 x Bn23); read Ah0,Bn01(t+1) from dn; stage A(t+2)h1 -> d
        if (t + 1 < NT) {
#pragma unroll
            for (int i = 0; i < 4; ++i) {
                aH0[i][0] = *(const f16x8*)(lbn + aOff + i * 4096 + gk0);
                aH0[i][1] = *(const f16x8*)(lbn + aOff + i * 4096 + gk1);
            }
#pragma unroll
            for (int j = 0; j < 2; ++j) {
                bN01[j][0] = *(const f16x8*)(lbn + bOff + j * 8192 + gk0);
                bN01[j][1] = *(const f16x8*)(lbn + bOff + j * 8192 + gk1);
            }
        }
        if (t + 2 < NT) stageA(t + 2, 1, d);
        __builtin_amdgcn_s_barrier();
        __builtin_amdgcn_s_setprio(1);
#pragma unroll
        for (int k = 0; k < 2; ++k)
#pragma unroll
            for (int i = 0; i < 4; ++i)
#pragma unroll
                for (int j = 0; j < 2; ++j)
                    acc[4 + i][2 + j] = __builtin_amdgcn_mfma_f32_16x16x32_f16(
                        aH1[i][k], bN23[j][k], acc[4 + i][2 + j], 0, 0, 0);
        __builtin_amdgcn_s_setprio(0);
        __builtin_amdgcn_s_barrier();
    }

    // Epilogue: C/D col = lane&15, row = (lane>>4)*4 + reg. Wave rows are
    // 16-interleaved: row(r) = rowBase + (r*2+wm)*16; col(j) = (j*4+wn)*16.
#pragma unroll
    for (int j = 0; j < 4; ++j) {
        const int col = colBase + (j * 4 + wn) * 16 + l15;
        const float bj = bias[col];
#pragma unroll
        for (int r = 0; r < 8; ++r) {
            const size_t rb = (size_t)(rowBase + (r * 2 + wm) * 16 + lq * 4) * NN + col;
#pragma unroll
            for (int v = 0; v < 4; ++v)
                out[rb + (size_t)v * NN] = fast_tanh(acc[r][j][v] + bj);
        }
    }
}

// ---------------------------------------------------------------------------
// Fallback (only if workspace too small): naive fp32 tiled GEMM.
__global__ void naive_gemm_kernel(const float* __restrict__ x,
                                  const float* __restrict__ W,
                                  const float* __restrict__ b,
                                  float* __restrict__ out) {
    __shared__ float xs[16][17], ws[16][17];
    int n = blockIdx.x * 16 + threadIdx.x;
    int m = blockIdx.y * 16 + threadIdx.y;
    float s = 0.f;
    for (int k0 = 0; k0 < DIM; k0 += 16) {
        xs[threadIdx.y][threadIdx.x] = x[(size_t)m * DIM + k0 + threadIdx.x];
        ws[threadIdx.y][threadIdx.x] =
            W[(size_t)(blockIdx.x * 16 + threadIdx.y) * DIM + k0 + threadIdx.x];
        __syncthreads();
#pragma unroll
        for (int kk = 0; kk < 16; kk++) s += xs[threadIdx.y][kk] * ws[threadIdx.x][kk];
        __syncthreads();
    }
    out[(size_t)m * NN + n] = tanhf(s + b[n]);
}

// ---------------------------------------------------------------------------
extern "C" void kernel_launch(void* const* d_in, const int* in_sizes, int n_in,
                              void* d_out, int out_size, void* d_ws, size_t ws_size,
                              hipStream_t stream) {
    const float* x = (const float*)d_in[0];
    const float* W = (const float*)d_in[1];
    const float* b = (const float*)d_in[2];
    float* out = (float*)d_out;

    const size_t need = A_BYTES + B_BYTES;   // 41.94 MB
    if (ws_size < need) {
        dim3 grid(NN / 16, SEQ / 16), block(16, 16);
        naive_gemm_kernel<<<grid, block, 0, stream>>>(x, W, b, out);
        return;
    }

    _Float16* Abuf = (_Float16*)d_ws;
    _Float16* Bbuf = Abuf + (size_t)SEQ * KEFF;

    convert_kernel<<<12288, 256, 0, stream>>>(x, W, (f16x4*)Abuf, (f16x4*)Bbuf);

    gemm_tanh_kernel<<<512, 512, 0, stream>>>(Abuf, Bbuf, b, out);
}